// Round 3
// baseline (556.220 us; speedup 1.0000x reference)
//
#include <hip/hip_runtime.h>
#include <hip/hip_bf16.h>

// PathEmbedding fused kernel for MI355X (gfx950). Round 3.
//
// Math (exact restructure): att[p,l] = h_l . u_p, u_p = h15 @ Wqk,
// Wqk = wq @ wk^T; context = (sum_l att_l h_l) @ wv.
//
// R3: x A-frags gathered straight from a pre-converted bf16 edge table into
// registers (prefetched 1 step ahead, reg-double-buffered) -> no x staging in
// LDS, 1 barrier/step. GRU weights pre-packed in B-frag order (one b128 load
// per frag). Gates: v_exp/v_rcp fast sigmoid/tanh, biases folded into MFMA
// accumulator init. h crosses waves via the 16-slot LDS hist (also feeds
// attention epilogue).
// Fragment layouts (HW-verified): A[m=lane&15][k=quad*8+j],
// B[k=quad*8+j][n=lane&15], C/D[row=quad*4+reg][col=lane&15].

#define NUM_EDGES 10000
#define NUM_PATHS 30000
#define T_PATHS 32
#define NTILES ((NUM_PATHS + T_PATHS - 1) / T_PATHS)  // 938 (last tile 16 rows)

typedef float f32x4 __attribute__((ext_vector_type(4)));
typedef short bf16x8 __attribute__((ext_vector_type(8)));

// half-up rounding: max error 0.5 ulp (ties always up), 2 VALU ops
__device__ __forceinline__ short f2bf(float f) {
    union { float f; unsigned u; } v; v.f = f;
    return (short)((v.u + 0x8000u) >> 16);
}
__device__ __forceinline__ float bf2f(short s) {
    union { unsigned u; float f; } v; v.u = ((unsigned)(unsigned short)s) << 16;
    return v.f;
}
__device__ __forceinline__ float fsig(float x) {
    // 1/(1+e^-x); saturates correctly at +-inf, no clamps needed
    return __builtin_amdgcn_rcpf(1.0f + __expf(-x));
}
__device__ __forceinline__ float ftanh(float x) {
    // 1 - 2/(e^{2x}+1)
    return 1.0f - 2.0f * __builtin_amdgcn_rcpf(1.0f + __expf(2.0f * x));
}
__device__ __forceinline__ int sel4(const int4 v, int c) {
    return (c & 1) ? ((c & 2) ? v.w : v.y) : ((c & 2) ? v.z : v.x);
}

// ---------- prep: Wqk = wq @ wk^T ----------
__global__ void wqk_kernel(const float* __restrict__ wq, const float* __restrict__ wk,
                           float* __restrict__ Wqk) {
    int id = blockIdx.x * 256 + threadIdx.x;
    int u = id >> 7, i = id & 127;
    float s = 0.f;
    #pragma unroll 8
    for (int v = 0; v < 128; ++v) s += wq[u * 128 + v] * wk[i * 128 + v];
    Wqk[u * 128 + i] = s;
}

// ---------- prep: bf16 edge table + packed GRU B-frags ----------
// wpk element index: ((f*8 + w)*64 + lane)*8 + j
//   f 0..7  = Bz[kc]  (z cols, k=f*32+quad*8+j over [x;h])
//   f 8..15 = Br[kc]  (r cols)
//   f 16..19= Bxh[kc] (cand, x side)   f 20..23 = Bhh[kc] (cand, h side)
#define PACK_THREADS 12288
#define CONV_CHUNKS 160000   // 10000*128/8
__global__ void prep_kernel(const float* __restrict__ inputs,
                            const float* __restrict__ Wx, const float* __restrict__ Wr,
                            short* __restrict__ tab, short* __restrict__ wpk) {
    int id = blockIdx.x * 256 + threadIdx.x;
    if (id < PACK_THREADS) {
        int f = id >> 9, rem = id & 511;
        int w = rem >> 6, lane = rem & 63;
        int quad = lane >> 4, c16 = lane & 15;
        int col = 16 * w + c16;
        short o[8];
        #pragma unroll
        for (int j = 0; j < 8; ++j) {
            float v;
            if (f < 16) {
                int k = (f & 7) * 32 + quad * 8 + j;          // 0..255 over [x;h]
                int cc = col + ((f < 8) ? 0 : 128);
                v = (k < 128) ? Wx[k * 384 + cc] : Wr[(k - 128) * 384 + cc];
            } else {
                int k = ((f - 16) & 3) * 32 + quad * 8 + j;   // 0..127
                v = (f < 20) ? Wx[k * 384 + 256 + col] : Wr[k * 384 + 256 + col];
            }
            o[j] = f2bf(v);
        }
        *(bf16x8*)&wpk[id * 8] = *(bf16x8*)o;
    }
    int cid = id - PACK_THREADS;
    if (cid >= 0 && cid < CONV_CHUNKS) {
        float4 a = *(const float4*)&inputs[cid * 8];
        float4 b = *(const float4*)&inputs[cid * 8 + 4];
        short o[8] = {f2bf(a.x), f2bf(a.y), f2bf(a.z), f2bf(a.w),
                      f2bf(b.x), f2bf(b.y), f2bf(b.z), f2bf(b.w)};
        *(bf16x8*)&tab[cid * 8] = *(bf16x8*)o;
    }
}

#define MFMA(a, b, c) __builtin_amdgcn_mfma_f32_16x16x32_bf16((a), (b), (c), 0, 0, 0)

#define ROWS 136            // padded row stride (shorts): 2-way-max LDS conflicts
#define HSLOT 4360          // 32*136+8: slot stride rotates banks by 4 words

__global__ __launch_bounds__(512, 2) void path_emb_kernel(
    const short* __restrict__ tab, const int* __restrict__ paths,
    const short* __restrict__ wpk,
    const float* __restrict__ bias_i, const float* __restrict__ bias_r,
    const float* __restrict__ Wqk, const float* __restrict__ wv,
    float* __restrict__ out)
{
    __shared__ __align__(16) short s_hist[16][HSLOT];  // h_0..h_15 bf16 (139,520 B)
    __shared__ __align__(16) short s_ea[T_PATHS * ROWS]; // epilogue hi buf (8,704 B)
    __shared__ __align__(16) short s_eb[T_PATHS * ROWS]; // epilogue lo buf (8,704 B)
    __shared__ float s_att[T_PATHS][20];                 // att f32       (2,560 B)
    // total 159,488 B

    const int tid  = threadIdx.x;
    const int w    = tid >> 6;
    const int lane = tid & 63;
    const int quad = lane >> 4;
    const int c16  = lane & 15;
    const int ucol = 16 * w + c16;

    const float bz  = bias_i[ucol] + bias_r[ucol];
    const float brr = bias_i[128 + ucol] + bias_r[128 + ucol];
    const float bxh = bias_i[256 + ucol];
    const float bhh = bias_r[256 + ucol];

    // persistent B-frags: one coalesced b128 each
    bf16x8 Ball[24];
    #pragma unroll
    for (int f = 0; f < 24; ++f)
        Ball[f] = *(const bf16x8*)&wpk[((f * 8 + w) * 64 + lane) * 8];

    for (int tile = blockIdx.x; tile < NTILES; tile += gridDim.x) {
        const int p0 = tile * T_PATHS;
        const int pr0 = min(p0 + c16, NUM_PATHS - 1);       // this lane's row m=c16
        const int pr1 = min(p0 + 16 + c16, NUM_PATHS - 1);  // row m=16+c16

        float hreg[8];
        #pragma unroll
        for (int i = 0; i < 8; ++i) hreg[i] = 0.f;

        int4 ei0 = *(const int4*)&paths[pr0 * 16];  // edges t=0..3
        int4 ei1 = *(const int4*)&paths[pr1 * 16];

        bf16x8 xf[2][2][4];
        { // gather x_0
            const short* b0 = tab + ei0.x * 128 + quad * 8;
            const short* b1 = tab + ei1.x * 128 + quad * 8;
            #pragma unroll
            for (int kc = 0; kc < 4; ++kc) {
                xf[0][0][kc] = *(const bf16x8*)(b0 + kc * 32);
                xf[0][1][kc] = *(const bf16x8*)(b1 + kc * 32);
            }
        }

        // ---------------- GRU: 16 steps, 1 barrier each ----------------
        for (int t = 0; t < 16; ++t) {
            if (t) __syncthreads();   // h_{t-1} visible; hist WAR safe

            // prefetch x_{t+1} into the other reg buffer
            if (t < 15) {
                int tn = t + 1;
                if (!(tn & 3)) {
                    ei0 = *(const int4*)&paths[pr0 * 16 + tn];
                    ei1 = *(const int4*)&paths[pr1 * 16 + tn];
                }
                int c = tn & 3;
                const short* b0 = tab + sel4(ei0, c) * 128 + quad * 8;
                const short* b1 = tab + sel4(ei1, c) * 128 + quad * 8;
                #pragma unroll
                for (int kc = 0; kc < 4; ++kc) {
                    xf[tn & 1][0][kc] = *(const bf16x8*)(b0 + kc * 32);
                    xf[tn & 1][1][kc] = *(const bf16x8*)(b1 + kc * 32);
                }
            }

            bf16x8 ah[2][4];
            if (t > 0) {
                #pragma unroll
                for (int mt = 0; mt < 2; ++mt)
                    #pragma unroll
                    for (int kc = 0; kc < 4; ++kc)
                        ah[mt][kc] = *(const bf16x8*)&s_hist[t - 1][(mt * 16 + c16) * ROWS + kc * 32 + quad * 8];
            }

            const int cur = t & 1;
            f32x4 az[2], ar[2], acx[2], ach[2];
            #pragma unroll
            for (int mt = 0; mt < 2; ++mt) {
                az[mt]  = (f32x4){bz, bz, bz, bz};
                ar[mt]  = (f32x4){brr, brr, brr, brr};
                acx[mt] = (f32x4){bxh, bxh, bxh, bxh};
                ach[mt] = (f32x4){bhh, bhh, bhh, bhh};
            }
            #pragma unroll
            for (int mt = 0; mt < 2; ++mt)
                #pragma unroll
                for (int kc = 0; kc < 4; ++kc) {
                    az[mt]  = MFMA(xf[cur][mt][kc], Ball[kc],      az[mt]);
                    ar[mt]  = MFMA(xf[cur][mt][kc], Ball[8 + kc],  ar[mt]);
                    acx[mt] = MFMA(xf[cur][mt][kc], Ball[16 + kc], acx[mt]);
                }
            if (t > 0) {
                #pragma unroll
                for (int mt = 0; mt < 2; ++mt)
                    #pragma unroll
                    for (int kc = 0; kc < 4; ++kc) {
                        az[mt]  = MFMA(ah[mt][kc], Ball[4 + kc],  az[mt]);
                        ar[mt]  = MFMA(ah[mt][kc], Ball[12 + kc], ar[mt]);
                        ach[mt] = MFMA(ah[mt][kc], Ball[20 + kc], ach[mt]);
                    }
            }

            // gates in-register; h_t bf16 -> hist (cross-wave exchange)
            #pragma unroll
            for (int mt = 0; mt < 2; ++mt)
                #pragma unroll
                for (int r = 0; r < 4; ++r) {
                    int i = mt * 4 + r;
                    float z    = fsig(az[mt][r]);
                    float rr   = fsig(ar[mt][r]);
                    float cand = ftanh(acx[mt][r] + rr * ach[mt][r]);
                    hreg[i] = cand + z * (hreg[i] - cand);
                    s_hist[t][(mt * 16 + quad * 4 + r) * ROWS + ucol] = f2bf(hreg[i]);
                }
        }

        // ---------------- epilogue: attention (linear form) ----------------
        // E0: h15 lo residual -> s_ea (own regs; no barrier needed before)
        #pragma unroll
        for (int mt = 0; mt < 2; ++mt)
            #pragma unroll
            for (int r = 0; r < 4; ++r) {
                float hf = hreg[mt * 4 + r];
                short hi = f2bf(hf);
                s_ea[(mt * 16 + quad * 4 + r) * ROWS + ucol] = f2bf(hf - bf2f(hi));
            }
        __syncthreads();  // b1: hist[15] + s_ea complete

        // E1: u = h15 @ Wqk (hi/lo split, 24 MFMAs)
        f32x4 uacc[2];
        { f32x4 zz = {0.f, 0.f, 0.f, 0.f}; uacc[0] = zz; uacc[1] = zz; }
        #pragma unroll
        for (int kc = 0; kc < 4; ++kc) {
            bf16x8 bhi, blo;
            #pragma unroll
            for (int j = 0; j < 8; ++j) {
                float v = Wqk[(kc * 32 + quad * 8 + j) * 128 + ucol];
                short h = f2bf(v);
                bhi[j] = h; blo[j] = f2bf(v - bf2f(h));
            }
            #pragma unroll
            for (int mt = 0; mt < 2; ++mt) {
                bf16x8 Ahi = *(const bf16x8*)&s_hist[15][(mt * 16 + c16) * ROWS + kc * 32 + quad * 8];
                bf16x8 Alo = *(const bf16x8*)&s_ea[(mt * 16 + c16) * ROWS + kc * 32 + quad * 8];
                uacc[mt] = MFMA(Ahi, bhi, uacc[mt]);
                uacc[mt] = MFMA(Ahi, blo, uacc[mt]);
                uacc[mt] = MFMA(Alo, bhi, uacc[mt]);
            }
        }
        __syncthreads();  // b2: E1's s_ea reads done

        // E2: u hi/lo (C-scatter)
        #pragma unroll
        for (int mt = 0; mt < 2; ++mt)
            #pragma unroll
            for (int r = 0; r < 4; ++r) {
                float v = uacc[mt][r];
                short hi = f2bf(v);
                int off = (mt * 16 + quad * 4 + r) * ROWS + ucol;
                s_ea[off] = hi;
                s_eb[off] = f2bf(v - bf2f(hi));
            }
        __syncthreads();  // b3

        // E3: att[p][l] = sum_u u[p][u] * hist_l[p][u]
        {
            int p = tid >> 4, l = tid & 15;
            const short* uh = &s_ea[p * ROWS];
            const short* ul = &s_eb[p * ROWS];
            const short* hh = &s_hist[l][p * ROWS];
            float a = 0.f;
            #pragma unroll
            for (int u8 = 0; u8 < 128; u8 += 8) {
                bf16x8 vh = *(const bf16x8*)&uh[u8];
                bf16x8 vl = *(const bf16x8*)&ul[u8];
                bf16x8 vt = *(const bf16x8*)&hh[u8];
                #pragma unroll
                for (int j = 0; j < 8; ++j)
                    a += (bf2f(vh[j]) + bf2f(vl[j])) * bf2f(vt[j]);
            }
            s_att[p][l] = a;
        }
        __syncthreads();  // b4

        // E4: ctx[p][v] = sum_l att[p][l] * hist_l[p][v]; hi/lo split
        {
            int p = tid >> 4, v0 = (tid & 15) * 8;
            float ctx[8];
            #pragma unroll
            for (int j = 0; j < 8; ++j) ctx[j] = 0.f;
            #pragma unroll
            for (int l = 0; l < 16; ++l) {
                float al = s_att[p][l];
                bf16x8 hv = *(const bf16x8*)&s_hist[l][p * ROWS + v0];
                #pragma unroll
                for (int j = 0; j < 8; ++j) ctx[j] += al * bf2f(hv[j]);
            }
            #pragma unroll
            for (int j = 0; j < 8; ++j) {
                short hi = f2bf(ctx[j]);
                s_ea[p * ROWS + v0 + j] = hi;
                s_eb[p * ROWS + v0 + j] = f2bf(ctx[j] - bf2f(hi));
            }
        }
        __syncthreads();  // b5: last hist readers done before next tile's step 0

        // E5: out = ctx @ wv (hi/lo split), guarded store
        f32x4 oacc[2];
        { f32x4 zz = {0.f, 0.f, 0.f, 0.f}; oacc[0] = zz; oacc[1] = zz; }
        #pragma unroll
        for (int kc = 0; kc < 4; ++kc) {
            bf16x8 bhi, blo;
            #pragma unroll
            for (int j = 0; j < 8; ++j) {
                float v = wv[(kc * 32 + quad * 8 + j) * 128 + ucol];
                short h = f2bf(v);
                bhi[j] = h; blo[j] = f2bf(v - bf2f(h));
            }
            #pragma unroll
            for (int mt = 0; mt < 2; ++mt) {
                bf16x8 Ahi = *(const bf16x8*)&s_ea[(mt * 16 + c16) * ROWS + kc * 32 + quad * 8];
                bf16x8 Alo = *(const bf16x8*)&s_eb[(mt * 16 + c16) * ROWS + kc * 32 + quad * 8];
                oacc[mt] = MFMA(Ahi, bhi, oacc[mt]);
                oacc[mt] = MFMA(Ahi, blo, oacc[mt]);
                oacc[mt] = MFMA(Alo, bhi, oacc[mt]);
            }
        }
        #pragma unroll
        for (int mt = 0; mt < 2; ++mt)
            #pragma unroll
            for (int r = 0; r < 4; ++r) {
                int prow = p0 + mt * 16 + quad * 4 + r;
                if (prow < NUM_PATHS) out[prow * 128 + ucol] = oacc[mt][r];
            }
    }
}

extern "C" void kernel_launch(void* const* d_in, const int* in_sizes, int n_in,
                              void* d_out, int out_size, void* d_ws, size_t ws_size,
                              hipStream_t stream) {
    const float* inputs = (const float*)d_in[0];
    const int*   paths  = (const int*)d_in[1];
    // d_in[2]=idx, d_in[3]=seqs: layout known (p*16+s), unused
    const float* wx  = (const float*)d_in[4];
    const float* wr  = (const float*)d_in[5];
    const float* bi  = (const float*)d_in[6];
    const float* br  = (const float*)d_in[7];
    const float* wq  = (const float*)d_in[8];
    const float* wk  = (const float*)d_in[9];
    const float* wvp = (const float*)d_in[10];

    // workspace layout (needs ~2.9 MB)
    char* ws = (char*)d_ws;
    float* Wqk = (float*)ws;                                  //    65,536 B
    short* tab = (short*)(ws + 65536);                        // 2,560,000 B
    short* wpk = (short*)(ws + 65536 + 2560000);              //   196,608 B

    wqk_kernel<<<64, 256, 0, stream>>>(wq, wk, Wqk);
    prep_kernel<<<(PACK_THREADS + CONV_CHUNKS + 255) / 256, 256, 0, stream>>>(
        inputs, wx, wr, tab, wpk);
    path_emb_kernel<<<256, 512, 0, stream>>>(tab, paths, wpk, bi, br, Wqk, wvp,
                                             (float*)d_out);
}

// Round 4
// 236.534 us; speedup vs baseline: 2.3515x; 2.3515x over previous
//
#include <hip/hip_runtime.h>
#include <hip/hip_bf16.h>

// PathEmbedding fused kernel for MI355X (gfx950). Round 4.
//
// Math (exact restructure): att[p,l] = h_l . u_p, u_p = h15 @ Wqk,
// Wqk = wq @ wk^T; context = (sum_l att_l h_l) @ wv.
//
// R4 = R2 dataflow (x staged in LDS, B-frags resident, gates in-register)
//    + bf16 edge table & pre-packed weight frags (prep kernel, no staging VALU)
//    + LDS x double-buffer -> 1 barrier/step
//    + fast gates (rcp/exp, no divides, biases folded into accum init)
// R3 post-mortem: long-lived register gather buffers caused scratch spills
// (WRITE_SIZE 986 MB) -> never hold gathered A-data in regs across steps.
// Fragment layouts (HW-verified): A[m=lane&15][k=quad*8+j],
// B[k=quad*8+j][n=lane&15], C/D[row=quad*4+reg][col=lane&15].

#define NUM_PATHS 30000
#define T_PATHS 32
#define NTILES ((NUM_PATHS + T_PATHS - 1) / T_PATHS)  // 938 (last tile 16 rows)

typedef float f32x4 __attribute__((ext_vector_type(4)));
typedef short bf16x8 __attribute__((ext_vector_type(8)));

// half-up rounding: max error 0.5 ulp, 2 VALU ops
__device__ __forceinline__ short f2bf(float f) {
    union { float f; unsigned u; } v; v.f = f;
    return (short)((v.u + 0x8000u) >> 16);
}
__device__ __forceinline__ float bf2f(short s) {
    union { unsigned u; float f; } v; v.u = ((unsigned)(unsigned short)s) << 16;
    return v.f;
}
__device__ __forceinline__ float fsig(float x) {
    return __builtin_amdgcn_rcpf(1.0f + __expf(-x));   // saturates correctly
}
__device__ __forceinline__ float ftanh(float x) {
    return 1.0f - 2.0f * __builtin_amdgcn_rcpf(1.0f + __expf(2.0f * x));
}

// ---------- prep: Wqk = wq @ wk^T ----------
__global__ void wqk_kernel(const float* __restrict__ wq, const float* __restrict__ wk,
                           float* __restrict__ Wqk) {
    int id = blockIdx.x * 256 + threadIdx.x;
    int u = id >> 7, i = id & 127;
    float s = 0.f;
    #pragma unroll 8
    for (int v = 0; v < 128; ++v) s += wq[u * 128 + v] * wk[i * 128 + v];
    Wqk[u * 128 + i] = s;
}

// ---------- prep: bf16 edge table + packed GRU B-frags ----------
// wpk element index: ((f*8 + w)*64 + lane)*8 + j
//   f 0..7  = Bz[kc] (z cols, k over [x;h])   f 8..15 = Br[kc] (r cols)
//   f 16..19= Bxh[kc] (cand, x)               f 20..23 = Bhh[kc] (cand, h)
#define PACK_THREADS 12288
#define CONV_CHUNKS 160000   // 10000*128/8
__global__ void prep_kernel(const float* __restrict__ inputs,
                            const float* __restrict__ Wx, const float* __restrict__ Wr,
                            short* __restrict__ tab, short* __restrict__ wpk) {
    int id = blockIdx.x * 256 + threadIdx.x;
    if (id < PACK_THREADS) {
        int f = id >> 9, rem = id & 511;
        int w = rem >> 6, lane = rem & 63;
        int quad = lane >> 4, c16 = lane & 15;
        int col = 16 * w + c16;
        short o[8];
        #pragma unroll
        for (int j = 0; j < 8; ++j) {
            float v;
            if (f < 16) {
                int k = (f & 7) * 32 + quad * 8 + j;          // 0..255 over [x;h]
                int cc = col + ((f < 8) ? 0 : 128);
                v = (k < 128) ? Wx[k * 384 + cc] : Wr[(k - 128) * 384 + cc];
            } else {
                int k = ((f - 16) & 3) * 32 + quad * 8 + j;   // 0..127
                v = (f < 20) ? Wx[k * 384 + 256 + col] : Wr[k * 384 + 256 + col];
            }
            o[j] = f2bf(v);
        }
        *(bf16x8*)&wpk[id * 8] = *(bf16x8*)o;
    }
    int cid = id - PACK_THREADS;
    if (cid >= 0 && cid < CONV_CHUNKS) {
        float4 a = *(const float4*)&inputs[cid * 8];
        float4 b = *(const float4*)&inputs[cid * 8 + 4];
        short o[8] = {f2bf(a.x), f2bf(a.y), f2bf(a.z), f2bf(a.w),
                      f2bf(b.x), f2bf(b.y), f2bf(b.z), f2bf(b.w)};
        *(bf16x8*)&tab[cid * 8] = *(bf16x8*)o;
    }
}

#define MFMA(a, b, c) __builtin_amdgcn_mfma_f32_16x16x32_bf16((a), (b), (c), 0, 0, 0)

#define ROWS 136            // padded row stride (shorts): <=2-way LDS conflicts
#define HSLOT 4360          // 32*136+8: slot stride rotates banks
#define XROWS (T_PATHS * ROWS)

__global__ __launch_bounds__(512, 2) void path_emb_kernel(
    const short* __restrict__ tab, const int* __restrict__ paths,
    const short* __restrict__ wpk,
    const float* __restrict__ bias_i, const float* __restrict__ bias_r,
    const float* __restrict__ Wqk, const float* __restrict__ wv,
    float* __restrict__ out)
{
    __shared__ __align__(16) short s_hist[16][HSLOT];  // h_0..h_15 bf16 (139,520 B)
    __shared__ __align__(16) short s_xb[2][XROWS];     // x dbuf / epilogue (17,408 B)
    __shared__ float s_att[T_PATHS][20];               // att f32          (2,560 B)
    // total 159,488 B -> 1 WG/CU
    short* const s_ea = s_xb[0];   // epilogue hi buf (aliases x dbuf)
    short* const s_eb = s_xb[1];   // epilogue lo buf

    const int tid  = threadIdx.x;
    const int w    = tid >> 6;
    const int lane = tid & 63;
    const int quad = lane >> 4;
    const int c16  = lane & 15;
    const int ucol = 16 * w + c16;
    const int srow = tid >> 4;          // staging row 0..31
    const int schunk = (tid & 15) * 8;  // staging chunk

    const float bz  = bias_i[ucol] + bias_r[ucol];
    const float brr = bias_i[128 + ucol] + bias_r[128 + ucol];
    const float bxh = bias_i[256 + ucol];
    const float bhh = bias_r[256 + ucol];

    // persistent B-frags: one coalesced b128 each (kept resident; compiler
    // places them in AGPRs -- A-frags below are short-lived LDS reads)
    bf16x8 Ball[24];
    #pragma unroll
    for (int f = 0; f < 24; ++f)
        Ball[f] = *(const bf16x8*)&wpk[((f * 8 + w) * 64 + lane) * 8];

    for (int tile = blockIdx.x; tile < NTILES; tile += gridDim.x) {
        const int p0 = tile * T_PATHS;
        const int spr = min(p0 + srow, NUM_PATHS - 1) * 16;  // this thread's path base

        __syncthreads();  // tile fence: prev epilogue LDS reads done
        {   // stage x_0 -> xb[0]
            int e = paths[spr];
            *(bf16x8*)&s_xb[0][srow * ROWS + schunk] = *(const bf16x8*)&tab[e * 128 + schunk];
        }

        float hreg[8];
        #pragma unroll
        for (int i = 0; i < 8; ++i) hreg[i] = 0.f;

        // ---------------- GRU: 16 steps, 1 barrier each ----------------
        for (int t = 0; t < 16; ++t) {
            __syncthreads();  // x_t staged, h_{t-1} visible, xb[(t+1)&1] free

            if (t < 15) {     // prefetch-stage x_{t+1} into other buffer
                int e = paths[spr + t + 1];
                *(bf16x8*)&s_xb[(t + 1) & 1][srow * ROWS + schunk] =
                    *(const bf16x8*)&tab[e * 128 + schunk];
            }

            bf16x8 ax[2][4], ah[2][4];
            #pragma unroll
            for (int mt = 0; mt < 2; ++mt)
                #pragma unroll
                for (int kc = 0; kc < 4; ++kc)
                    ax[mt][kc] = *(const bf16x8*)&s_xb[t & 1][(mt * 16 + c16) * ROWS + kc * 32 + quad * 8];
            if (t > 0) {
                #pragma unroll
                for (int mt = 0; mt < 2; ++mt)
                    #pragma unroll
                    for (int kc = 0; kc < 4; ++kc)
                        ah[mt][kc] = *(const bf16x8*)&s_hist[t - 1][(mt * 16 + c16) * ROWS + kc * 32 + quad * 8];
            }

            f32x4 az[2], ar[2], acx[2], ach[2];
            #pragma unroll
            for (int mt = 0; mt < 2; ++mt) {
                az[mt]  = (f32x4){bz, bz, bz, bz};
                ar[mt]  = (f32x4){brr, brr, brr, brr};
                acx[mt] = (f32x4){bxh, bxh, bxh, bxh};
                ach[mt] = (f32x4){bhh, bhh, bhh, bhh};
            }
            #pragma unroll
            for (int mt = 0; mt < 2; ++mt)
                #pragma unroll
                for (int kc = 0; kc < 4; ++kc) {
                    az[mt]  = MFMA(ax[mt][kc], Ball[kc],      az[mt]);
                    ar[mt]  = MFMA(ax[mt][kc], Ball[8 + kc],  ar[mt]);
                    acx[mt] = MFMA(ax[mt][kc], Ball[16 + kc], acx[mt]);
                }
            if (t > 0) {
                #pragma unroll
                for (int mt = 0; mt < 2; ++mt)
                    #pragma unroll
                    for (int kc = 0; kc < 4; ++kc) {
                        az[mt]  = MFMA(ah[mt][kc], Ball[4 + kc],  az[mt]);
                        ar[mt]  = MFMA(ah[mt][kc], Ball[12 + kc], ar[mt]);
                        ach[mt] = MFMA(ah[mt][kc], Ball[20 + kc], ach[mt]);
                    }
            }

            // gates in-register; h_t bf16 -> hist (cross-wave exchange)
            #pragma unroll
            for (int mt = 0; mt < 2; ++mt)
                #pragma unroll
                for (int r = 0; r < 4; ++r) {
                    int i = mt * 4 + r;
                    float z    = fsig(az[mt][r]);
                    float rr   = fsig(ar[mt][r]);
                    float cand = ftanh(acx[mt][r] + rr * ach[mt][r]);
                    hreg[i] = cand + z * (hreg[i] - cand);
                    s_hist[t][(mt * 16 + quad * 4 + r) * ROWS + ucol] = f2bf(hreg[i]);
                }
        }

        // ---------------- epilogue: attention (linear form) ----------------
        // E0: h15 lo residual -> s_ea (=xb0; x_15 lives in xb1, no conflict)
        #pragma unroll
        for (int mt = 0; mt < 2; ++mt)
            #pragma unroll
            for (int r = 0; r < 4; ++r) {
                float hf = hreg[mt * 4 + r];
                short hi = f2bf(hf);
                s_ea[(mt * 16 + quad * 4 + r) * ROWS + ucol] = f2bf(hf - bf2f(hi));
            }
        __syncthreads();  // b1: hist[15] + s_ea complete; window-15 xb reads done

        // E1: u = h15 @ Wqk (hi/lo split, 24 MFMAs)
        f32x4 uacc[2];
        { f32x4 zz = {0.f, 0.f, 0.f, 0.f}; uacc[0] = zz; uacc[1] = zz; }
        #pragma unroll
        for (int kc = 0; kc < 4; ++kc) {
            bf16x8 bhi, blo;
            #pragma unroll
            for (int j = 0; j < 8; ++j) {
                float v = Wqk[(kc * 32 + quad * 8 + j) * 128 + ucol];
                short h = f2bf(v);
                bhi[j] = h; blo[j] = f2bf(v - bf2f(h));
            }
            #pragma unroll
            for (int mt = 0; mt < 2; ++mt) {
                bf16x8 Ahi = *(const bf16x8*)&s_hist[15][(mt * 16 + c16) * ROWS + kc * 32 + quad * 8];
                bf16x8 Alo = *(const bf16x8*)&s_ea[(mt * 16 + c16) * ROWS + kc * 32 + quad * 8];
                uacc[mt] = MFMA(Ahi, bhi, uacc[mt]);
                uacc[mt] = MFMA(Ahi, blo, uacc[mt]);
                uacc[mt] = MFMA(Alo, bhi, uacc[mt]);
            }
        }
        __syncthreads();  // b2: E1's s_ea reads done

        // E2: u hi/lo (C-scatter)
        #pragma unroll
        for (int mt = 0; mt < 2; ++mt)
            #pragma unroll
            for (int r = 0; r < 4; ++r) {
                float v = uacc[mt][r];
                short hi = f2bf(v);
                int off = (mt * 16 + quad * 4 + r) * ROWS + ucol;
                s_ea[off] = hi;
                s_eb[off] = f2bf(v - bf2f(hi));
            }
        __syncthreads();  // b3

        // E3: att[p][l] = sum_u u[p][u] * hist_l[p][u]
        {
            int p = tid >> 4, l = tid & 15;
            const short* uh = &s_ea[p * ROWS];
            const short* ul = &s_eb[p * ROWS];
            const short* hh = &s_hist[l][p * ROWS];
            float a = 0.f;
            #pragma unroll
            for (int u8 = 0; u8 < 128; u8 += 8) {
                bf16x8 vh = *(const bf16x8*)&uh[u8];
                bf16x8 vl = *(const bf16x8*)&ul[u8];
                bf16x8 vt = *(const bf16x8*)&hh[u8];
                #pragma unroll
                for (int j = 0; j < 8; ++j)
                    a += (bf2f(vh[j]) + bf2f(vl[j])) * bf2f(vt[j]);
            }
            s_att[p][l] = a;
        }
        __syncthreads();  // b4

        // E4: ctx[p][v] = sum_l att[p][l] * hist_l[p][v]; hi/lo split
        {
            int p = tid >> 4, v0 = (tid & 15) * 8;
            float ctx[8];
            #pragma unroll
            for (int j = 0; j < 8; ++j) ctx[j] = 0.f;
            #pragma unroll
            for (int l = 0; l < 16; ++l) {
                float al = s_att[p][l];
                bf16x8 hv = *(const bf16x8*)&s_hist[l][p * ROWS + v0];
                #pragma unroll
                for (int j = 0; j < 8; ++j) ctx[j] += al * bf2f(hv[j]);
            }
            #pragma unroll
            for (int j = 0; j < 8; ++j) {
                short hi = f2bf(ctx[j]);
                s_ea[p * ROWS + v0 + j] = hi;
                s_eb[p * ROWS + v0 + j] = f2bf(ctx[j] - bf2f(hi));
            }
        }
        __syncthreads();  // b5

        // E5: out = ctx @ wv (hi/lo split), guarded store
        f32x4 oacc[2];
        { f32x4 zz = {0.f, 0.f, 0.f, 0.f}; oacc[0] = zz; oacc[1] = zz; }
        #pragma unroll
        for (int kc = 0; kc < 4; ++kc) {
            bf16x8 bhi, blo;
            #pragma unroll
            for (int j = 0; j < 8; ++j) {
                float v = wv[(kc * 32 + quad * 8 + j) * 128 + ucol];
                short h = f2bf(v);
                bhi[j] = h; blo[j] = f2bf(v - bf2f(h));
            }
            #pragma unroll
            for (int mt = 0; mt < 2; ++mt) {
                bf16x8 Ahi = *(const bf16x8*)&s_ea[(mt * 16 + c16) * ROWS + kc * 32 + quad * 8];
                bf16x8 Alo = *(const bf16x8*)&s_eb[(mt * 16 + c16) * ROWS + kc * 32 + quad * 8];
                oacc[mt] = MFMA(Ahi, bhi, oacc[mt]);
                oacc[mt] = MFMA(Ahi, blo, oacc[mt]);
                oacc[mt] = MFMA(Alo, bhi, oacc[mt]);
            }
        }
        #pragma unroll
        for (int mt = 0; mt < 2; ++mt)
            #pragma unroll
            for (int r = 0; r < 4; ++r) {
                int prow = p0 + mt * 16 + quad * 4 + r;
                if (prow < NUM_PATHS) out[prow * 128 + ucol] = oacc[mt][r];
            }
    }
}

extern "C" void kernel_launch(void* const* d_in, const int* in_sizes, int n_in,
                              void* d_out, int out_size, void* d_ws, size_t ws_size,
                              hipStream_t stream) {
    const float* inputs = (const float*)d_in[0];
    const int*   paths  = (const int*)d_in[1];
    // d_in[2]=idx, d_in[3]=seqs: layout known (p*16+s), unused
    const float* wx  = (const float*)d_in[4];
    const float* wr  = (const float*)d_in[5];
    const float* bi  = (const float*)d_in[6];
    const float* br  = (const float*)d_in[7];
    const float* wq  = (const float*)d_in[8];
    const float* wk  = (const float*)d_in[9];
    const float* wvp = (const float*)d_in[10];

    // workspace layout (~2.9 MB)
    char* ws = (char*)d_ws;
    float* Wqk = (float*)ws;                       //    65,536 B
    short* tab = (short*)(ws + 65536);             // 2,560,000 B
    short* wpk = (short*)(ws + 65536 + 2560000);   //   196,608 B

    wqk_kernel<<<64, 256, 0, stream>>>(wq, wk, Wqk);
    prep_kernel<<<(PACK_THREADS + CONV_CHUNKS + 255) / 256, 256, 0, stream>>>(
        inputs, wx, wr, tab, wpk);
    path_emb_kernel<<<256, 512, 0, stream>>>(tab, paths, wpk, bi, br, Wqk, wvp,
                                             (float*)d_out);
}

// Round 5
// 223.366 us; speedup vs baseline: 2.4902x; 1.0590x over previous
//
#include <hip/hip_runtime.h>

// PathEmbedding fused kernel for MI355X (gfx950). Round 5.
//
// Math (exact restructure): att[p,l] = h_l . u_p, u_p = h15 @ Wqk,
// Wqk[k][i] = sum_v wq[k,v] wk[i,v]; context = (sum_l att_l h_l) @ wv.
//
// R5 = R4 dataflow with TWO independent 16-path tiles interleaved per WG:
// tile B's MFMAs overlap tile A's gate VALU/transcendental chains within
// each wave (MFMA issue is non-blocking), and one barrier serves both
// tiles -> barriers per path-step halved. Epilogue weights (Wqk, wv)
// pre-packed hi/lo in B-frag order by prep (which also computes Wqk
// directly -> 2 launches total). 30000 % 16 == 0: no ragged guards.
// R3 lesson: no long-lived gathered A-data in regs (spills).
// Fragment layouts (HW-verified): A[m=lane&15][k=quad*8+j],
// B[k=quad*8+j][n=lane&15], C/D[row=quad*4+reg][col=lane&15].

#define NUM_PATHS 30000
#define T 16
#define NTILES 1875
#define NPAIRS 938

typedef float f32x4 __attribute__((ext_vector_type(4)));
typedef short bf16x8 __attribute__((ext_vector_type(8)));

// half-up rounding: max error 0.5 ulp, 2 VALU ops
__device__ __forceinline__ short f2bf(float f) {
    union { float f; unsigned u; } v; v.f = f;
    return (short)((v.u + 0x8000u) >> 16);
}
__device__ __forceinline__ float bf2f(short s) {
    union { unsigned u; float f; } v; v.u = ((unsigned)(unsigned short)s) << 16;
    return v.f;
}
__device__ __forceinline__ float fsig(float x) {
    return __builtin_amdgcn_rcpf(1.0f + __expf(-x));   // saturates correctly
}
__device__ __forceinline__ float ftanhf_(float x) {
    return 1.0f - 2.0f * __builtin_amdgcn_rcpf(1.0f + __expf(2.0f * x));
}

// ---------- prep: bf16 edge table + all packed B-frags ----------
// wpk frag slot f, element ((f*8 + w)*64 + lane)*8 + j :
//   f 0..7  = Bz[kc] (k over [x;h])   f 8..15 = Br[kc]
//   f 16..19= Bxh[kc] (x side)        f 20..23 = Bhh[kc] (h side)
//   f 24..27= Bqk_hi[kc]              f 28..31 = Bqk_lo[kc]   (Wqk = wq.wk^T)
//   f 32..35= Bwv_hi[kc]              f 36..39 = Bwv_lo[kc]
#define GRU_T 12288
#define QK_T 16384
#define WV_T 2048
#define TAB_C 160000    // 10000*128/8
__global__ void prep_kernel(const float* __restrict__ inputs,
                            const float* __restrict__ Wx, const float* __restrict__ Wr,
                            const float* __restrict__ wq, const float* __restrict__ wk,
                            const float* __restrict__ wv,
                            short* __restrict__ tab, short* __restrict__ wpk) {
    int id = blockIdx.x * 256 + threadIdx.x;
    if (id < GRU_T) {
        int f = id >> 9, rem = id & 511;
        int w = rem >> 6, lane = rem & 63;
        int quad = lane >> 4, c16 = lane & 15;
        int col = 16 * w + c16;
        short o[8];
        #pragma unroll
        for (int j = 0; j < 8; ++j) {
            float v;
            if (f < 16) {
                int k = (f & 7) * 32 + quad * 8 + j;          // 0..255 over [x;h]
                int cc = col + ((f < 8) ? 0 : 128);
                v = (k < 128) ? Wx[k * 384 + cc] : Wr[(k - 128) * 384 + cc];
            } else {
                int k = ((f - 16) & 3) * 32 + quad * 8 + j;   // 0..127
                v = (f < 20) ? Wx[k * 384 + 256 + col] : Wr[k * 384 + 256 + col];
            }
            o[j] = f2bf(v);
        }
        *(bf16x8*)&wpk[id * 8] = *(bf16x8*)o;
        return;
    }
    if (id < GRU_T + QK_T) {
        // one thread per Bqk element: dot(wq[k,:], wk[col,:]) -> hi/lo
        int t2 = id - GRU_T;
        int j = t2 & 7, lane = (t2 >> 3) & 63, w = (t2 >> 9) & 7, kc = t2 >> 12;
        int quad = lane >> 4, c16 = lane & 15, col = 16 * w + c16;
        int k = kc * 32 + quad * 8 + j;
        const float* qr = wq + k * 128;
        const float* kr = wk + col * 128;
        float s = 0.f;
        #pragma unroll 8
        for (int vv = 0; vv < 128; ++vv) s += qr[vv] * kr[vv];
        short hi = f2bf(s);
        wpk[(((24 + kc) * 8 + w) * 64 + lane) * 8 + j] = hi;
        wpk[(((28 + kc) * 8 + w) * 64 + lane) * 8 + j] = f2bf(s - bf2f(hi));
        return;
    }
    if (id < GRU_T + QK_T + WV_T) {
        int t2 = id - GRU_T - QK_T;
        int lane = t2 & 63, w = (t2 >> 6) & 7, kc = t2 >> 9;
        int quad = lane >> 4, c16 = lane & 15, col = 16 * w + c16;
        short hi8[8], lo8[8];
        #pragma unroll
        for (int j = 0; j < 8; ++j) {
            float v = wv[(kc * 32 + quad * 8 + j) * 128 + col];
            hi8[j] = f2bf(v);
            lo8[j] = f2bf(v - bf2f(hi8[j]));
        }
        *(bf16x8*)&wpk[(((32 + kc) * 8 + w) * 64 + lane) * 8] = *(bf16x8*)hi8;
        *(bf16x8*)&wpk[(((36 + kc) * 8 + w) * 64 + lane) * 8] = *(bf16x8*)lo8;
        return;
    }
    int cid = id - (GRU_T + QK_T + WV_T);
    if (cid < TAB_C) {
        float4 a = *(const float4*)&inputs[cid * 8];
        float4 b = *(const float4*)&inputs[cid * 8 + 4];
        short o[8] = {f2bf(a.x), f2bf(a.y), f2bf(a.z), f2bf(a.w),
                      f2bf(b.x), f2bf(b.y), f2bf(b.z), f2bf(b.w)};
        *(bf16x8*)&tab[cid * 8] = *(bf16x8*)o;
    }
}

#define MFMA(a, b, c) __builtin_amdgcn_mfma_f32_16x16x32_bf16((a), (b), (c), 0, 0, 0)

#define ROWS 136    // padded row stride (shorts): <=2-way LDS conflicts
#define HSLOT 2184  // 16*136+8: +4-word slot rotation (fixes E3 l-lane conflicts)

__global__ __launch_bounds__(512, 2) void path_emb_kernel(
    const short* __restrict__ tab, const int* __restrict__ paths,
    const short* __restrict__ wpk,
    const float* __restrict__ bias_i, const float* __restrict__ bias_r,
    float* __restrict__ out)
{
    __shared__ __align__(16) short s_hist[2][16][HSLOT]; // per-tile h history (139,776 B)
    __shared__ __align__(16) short s_xb[2][2][T * ROWS]; // [tile][buf] x / epi (17,408 B)
    __shared__ float s_att[2][16][20];                   //                     (2,560 B)
    // total 159,744 B -> 1 WG/CU

    const int tid  = threadIdx.x;
    const int w    = tid >> 6;
    const int lane = tid & 63;
    const int quad = lane >> 4;
    const int c16  = lane & 15;
    const int ucol = 16 * w + c16;
    const int st   = tid >> 8;           // staging tile 0/1
    const int rid  = tid & 255;
    const int srow = rid >> 4;           // staging row 0..15
    const int schunk = (rid & 15) * 8;   // staging chunk

    const float bz  = bias_i[ucol] + bias_r[ucol];
    const float brr = bias_i[128 + ucol] + bias_r[128 + ucol];
    const float bxh = bias_i[256 + ucol];
    const float bhh = bias_r[256 + ucol];

    // persistent GRU B-frags (one b128 each; land in AGPRs)
    bf16x8 Ball[24];
    #pragma unroll
    for (int f = 0; f < 24; ++f)
        Ball[f] = *(const bf16x8*)&wpk[((f * 8 + w) * 64 + lane) * 8];

    for (int pi = blockIdx.x; pi < NPAIRS; pi += gridDim.x) {
        const int tA = 2 * pi;
        const int tB = (2 * pi + 1 < NTILES) ? 2 * pi + 1 : NTILES - 1;
        const int p0A = tA * T, p0B = tB * T;
        const int spr = ((st ? p0B : p0A) + srow) * 16;

        __syncthreads();  // pair fence: prev epilogue LDS reads done
        {   // stage x_0 for own tile
            int e = paths[spr];
            *(bf16x8*)&s_xb[st][0][srow * ROWS + schunk] = *(const bf16x8*)&tab[e * 128 + schunk];
        }

        float hA[4] = {0.f, 0.f, 0.f, 0.f}, hB[4] = {0.f, 0.f, 0.f, 0.f};

        // ---------------- GRU: 16 steps, 1 barrier each, 2 tiles ----------------
        for (int t = 0; t < 16; ++t) {
            __syncthreads();  // x_t staged, h_{t-1} visible, other x-buf free

            if (t < 15) {     // prefetch-stage x_{t+1}
                int e = paths[spr + t + 1];
                *(bf16x8*)&s_xb[st][(t + 1) & 1][srow * ROWS + schunk] =
                    *(const bf16x8*)&tab[e * 128 + schunk];
            }

            bf16x8 axA[4], axB[4], ahA[4], ahB[4];
            #pragma unroll
            for (int kc = 0; kc < 4; ++kc) {
                axA[kc] = *(const bf16x8*)&s_xb[0][t & 1][c16 * ROWS + kc * 32 + quad * 8];
                axB[kc] = *(const bf16x8*)&s_xb[1][t & 1][c16 * ROWS + kc * 32 + quad * 8];
            }
            if (t > 0) {
                #pragma unroll
                for (int kc = 0; kc < 4; ++kc) {
                    ahA[kc] = *(const bf16x8*)&s_hist[0][t - 1][c16 * ROWS + kc * 32 + quad * 8];
                    ahB[kc] = *(const bf16x8*)&s_hist[1][t - 1][c16 * ROWS + kc * 32 + quad * 8];
                }
            }

            f32x4 azA = {bz, bz, bz, bz},    azB = azA;
            f32x4 arA = {brr, brr, brr, brr}, arB = arA;
            f32x4 acxA = {bxh, bxh, bxh, bxh}, acxB = acxA;
            f32x4 achA = {bhh, bhh, bhh, bhh}, achB = achA;

            #pragma unroll
            for (int kc = 0; kc < 4; ++kc) {
                azA  = MFMA(axA[kc], Ball[kc],      azA);
                azB  = MFMA(axB[kc], Ball[kc],      azB);
                arA  = MFMA(axA[kc], Ball[8 + kc],  arA);
                arB  = MFMA(axB[kc], Ball[8 + kc],  arB);
                acxA = MFMA(axA[kc], Ball[16 + kc], acxA);
                acxB = MFMA(axB[kc], Ball[16 + kc], acxB);
            }
            if (t > 0) {
                #pragma unroll
                for (int kc = 0; kc < 4; ++kc) {
                    azA  = MFMA(ahA[kc], Ball[4 + kc],  azA);
                    azB  = MFMA(ahB[kc], Ball[4 + kc],  azB);
                    arA  = MFMA(ahA[kc], Ball[12 + kc], arA);
                    arB  = MFMA(ahB[kc], Ball[12 + kc], arB);
                    achA = MFMA(ahA[kc], Ball[20 + kc], achA);
                    achB = MFMA(ahB[kc], Ball[20 + kc], achB);
                }
            }

            // gates in-register (tile A first: its accs retire first; B's MFMAs
            // still drain in the pipe meanwhile)
            #pragma unroll
            for (int r = 0; r < 4; ++r) {
                float z    = fsig(azA[r]);
                float rr   = fsig(arA[r]);
                float cand = ftanhf_(acxA[r] + rr * achA[r]);
                hA[r] = cand + z * (hA[r] - cand);
                s_hist[0][t][(quad * 4 + r) * ROWS + ucol] = f2bf(hA[r]);
            }
            #pragma unroll
            for (int r = 0; r < 4; ++r) {
                float z    = fsig(azB[r]);
                float rr   = fsig(arB[r]);
                float cand = ftanhf_(acxB[r] + rr * achB[r]);
                hB[r] = cand + z * (hB[r] - cand);
                s_hist[1][t][(quad * 4 + r) * ROWS + ucol] = f2bf(hB[r]);
            }
        }

        // ---------------- epilogue (both tiles) ----------------
        // E0: h15 lo residual -> xb[tile][0]  (xb[*][0] last read at t=14)
        #pragma unroll
        for (int r = 0; r < 4; ++r) {
            float hf = hA[r]; short hi = f2bf(hf);
            s_xb[0][0][(quad * 4 + r) * ROWS + ucol] = f2bf(hf - bf2f(hi));
            hf = hB[r]; hi = f2bf(hf);
            s_xb[1][0][(quad * 4 + r) * ROWS + ucol] = f2bf(hf - bf2f(hi));
        }
        __syncthreads();  // b1: hist[15] + residuals visible

        // E1: u = h15 @ Wqk (hi/lo split, 12 MFMAs per tile)
        f32x4 uA = {0.f, 0.f, 0.f, 0.f}, uB = uA;
        #pragma unroll
        for (int kc = 0; kc < 4; ++kc) {
            bf16x8 bqh = *(const bf16x8*)&wpk[(((24 + kc) * 8 + w) * 64 + lane) * 8];
            bf16x8 bql = *(const bf16x8*)&wpk[(((28 + kc) * 8 + w) * 64 + lane) * 8];
            bf16x8 AhA = *(const bf16x8*)&s_hist[0][15][c16 * ROWS + kc * 32 + quad * 8];
            bf16x8 AlA = *(const bf16x8*)&s_xb[0][0][c16 * ROWS + kc * 32 + quad * 8];
            bf16x8 AhB = *(const bf16x8*)&s_hist[1][15][c16 * ROWS + kc * 32 + quad * 8];
            bf16x8 AlB = *(const bf16x8*)&s_xb[1][0][c16 * ROWS + kc * 32 + quad * 8];
            uA = MFMA(AhA, bqh, uA); uA = MFMA(AhA, bql, uA); uA = MFMA(AlA, bqh, uA);
            uB = MFMA(AhB, bqh, uB); uB = MFMA(AhB, bql, uB); uB = MFMA(AlB, bqh, uB);
        }
        __syncthreads();  // b2: E1's xb reads done

        // E2: u hi/lo (C-scatter)
        #pragma unroll
        for (int r = 0; r < 4; ++r) {
            int off = (quad * 4 + r) * ROWS + ucol;
            float v = uA[r]; short hi = f2bf(v);
            s_xb[0][0][off] = hi; s_xb[0][1][off] = f2bf(v - bf2f(hi));
            v = uB[r]; hi = f2bf(v);
            s_xb[1][0][off] = hi; s_xb[1][1][off] = f2bf(v - bf2f(hi));
        }
        __syncthreads();  // b3

        // E3: att[p][l] = sum_u u[p][u] * hist_l[p][u]   (thread <-> (tile,p,l))
        {
            int et = tid >> 8, p = (tid >> 4) & 15, l = tid & 15;
            const short* uh = &s_xb[et][0][p * ROWS];
            const short* ul = &s_xb[et][1][p * ROWS];
            const short* hh = &s_hist[et][l][p * ROWS];
            float a = 0.f;
            #pragma unroll
            for (int u8 = 0; u8 < 128; u8 += 8) {
                bf16x8 vh = *(const bf16x8*)&uh[u8];
                bf16x8 vl = *(const bf16x8*)&ul[u8];
                bf16x8 vt = *(const bf16x8*)&hh[u8];
                #pragma unroll
                for (int j = 0; j < 8; ++j)
                    a += (bf2f(vh[j]) + bf2f(vl[j])) * bf2f(vt[j]);
            }
            s_att[et][p][l] = a;
        }
        __syncthreads();  // b4

        // E4: ctx[p][v] = sum_l att[p][l] * hist_l[p][v]; hi/lo split
        {
            int et = tid >> 8, p = (tid >> 4) & 15, v0 = (tid & 15) * 8;
            float ctx[8];
            #pragma unroll
            for (int j = 0; j < 8; ++j) ctx[j] = 0.f;
            #pragma unroll
            for (int l = 0; l < 16; ++l) {
                float al = s_att[et][p][l];
                bf16x8 hv = *(const bf16x8*)&s_hist[et][l][p * ROWS + v0];
                #pragma unroll
                for (int j = 0; j < 8; ++j) ctx[j] += al * bf2f(hv[j]);
            }
            #pragma unroll
            for (int j = 0; j < 8; ++j) {
                short hi = f2bf(ctx[j]);
                s_xb[et][0][p * ROWS + v0 + j] = hi;
                s_xb[et][1][p * ROWS + v0 + j] = f2bf(ctx[j] - bf2f(hi));
            }
        }
        __syncthreads();  // b5

        // E5: out = ctx @ wv (hi/lo split), both tiles
        f32x4 oA = {0.f, 0.f, 0.f, 0.f}, oB = oA;
        #pragma unroll
        for (int kc = 0; kc < 4; ++kc) {
            bf16x8 bwh = *(const bf16x8*)&wpk[(((32 + kc) * 8 + w) * 64 + lane) * 8];
            bf16x8 bwl = *(const bf16x8*)&wpk[(((36 + kc) * 8 + w) * 64 + lane) * 8];
            bf16x8 AhA = *(const bf16x8*)&s_xb[0][0][c16 * ROWS + kc * 32 + quad * 8];
            bf16x8 AlA = *(const bf16x8*)&s_xb[0][1][c16 * ROWS + kc * 32 + quad * 8];
            bf16x8 AhB = *(const bf16x8*)&s_xb[1][0][c16 * ROWS + kc * 32 + quad * 8];
            bf16x8 AlB = *(const bf16x8*)&s_xb[1][1][c16 * ROWS + kc * 32 + quad * 8];
            oA = MFMA(AhA, bwh, oA); oA = MFMA(AhA, bwl, oA); oA = MFMA(AlA, bwh, oA);
            oB = MFMA(AhB, bwh, oB); oB = MFMA(AhB, bwl, oB); oB = MFMA(AlB, bwh, oB);
        }
        #pragma unroll
        for (int r = 0; r < 4; ++r) {
            out[(p0A + quad * 4 + r) * 128 + ucol] = oA[r];
            out[(p0B + quad * 4 + r) * 128 + ucol] = oB[r];  // dup pair: same values
        }
    }
}

extern "C" void kernel_launch(void* const* d_in, const int* in_sizes, int n_in,
                              void* d_out, int out_size, void* d_ws, size_t ws_size,
                              hipStream_t stream) {
    const float* inputs = (const float*)d_in[0];
    const int*   paths  = (const int*)d_in[1];
    // d_in[2]=idx, d_in[3]=seqs: layout known (p*16+s), unused
    const float* wx  = (const float*)d_in[4];
    const float* wr  = (const float*)d_in[5];
    const float* bi  = (const float*)d_in[6];
    const float* br  = (const float*)d_in[7];
    const float* wq  = (const float*)d_in[8];
    const float* wk  = (const float*)d_in[9];
    const float* wvp = (const float*)d_in[10];

    // workspace: tab 2,560,000 B | wpk 327,680 B
    char* ws = (char*)d_ws;
    short* tab = (short*)ws;
    short* wpk = (short*)(ws + 2560000);

    int prep_n = GRU_T + QK_T + WV_T + TAB_C;
    prep_kernel<<<(prep_n + 255) / 256, 256, 0, stream>>>(
        inputs, wx, wr, wq, wk, wvp, tab, wpk);
    path_emb_kernel<<<256, 512, 0, stream>>>(tab, paths, wpk, bi, br, (float*)d_out);
}